// Round 22
// baseline (129.077 us; speedup 1.0000x reference)
//
#include <hip/hip_runtime.h>

// VQ-VAE codebook quantization — R22: R21 with the phase-3 OOB fix (base4 was
//   blockIdx.x*4096 from the 512-block version; must be *1024 for 2048 blocks).
//   combine_rescore_gather: 2048 blocks x 16 rows (8 blocks/CU), batched MLP
//   phase-3 stream. mm = R11 verbatim. 4 launches.
//   x: [32, 256, 32, 32] f32 -> z: [N=32768, D=256]; W: [1024, 256] f32
//   idx[n] = argmin_k (|w_k|^2 - 2 z_n.w_k)
//   bf16 3-term split (per-chunk: hh, lh, hl); rows with (second - best) <= MARGIN
//   exactly rescored in fp32 (MARGIN = 0.0039 ~ 5.7 sigma of split error).
// Fragment-major global layout: each 16-row x 32-dim MFMA fragment is 1 KB
// contiguous in exact lane order (ushort idx = ((tile*8 + ch)*8 + fr)*512 + lane*8).
// Outputs flat f32: z_q (8388608), idx-as-float (32768), loss (1)

#define N_ROWS 32768
#define K_CODES 1024
#define D_DIM 256
#define MARGIN 0.00390625f

using f32x4  = __attribute__((ext_vector_type(4))) float;
using bf16x8 = __attribute__((ext_vector_type(8))) short;

__device__ __forceinline__ unsigned int rne_bf16(float f) {
    unsigned int u = __float_as_uint(f);
    return (u + 0x7FFFu + ((u >> 16) & 1u)) >> 16;   // round-to-nearest-even bf16 bits
}

// ---------------- fused: convz (blocks 0..2047) + prep (blocks 2048..2303) ----------------
__global__ void prep_convz_kernel(const float* __restrict__ x, const float* __restrict__ W,
                                  float* __restrict__ wsq,
                                  unsigned short* __restrict__ Wfh, unsigned short* __restrict__ Wfl,
                                  unsigned short* __restrict__ Zfh, unsigned short* __restrict__ Zfl,
                                  float* __restrict__ loss_acc) {
    __shared__ float tile[64][65];
    const int t = threadIdx.x;

    if (blockIdx.x >= 2048) {
        // ---------------- prep part ----------------
        int p = (blockIdx.x - 2048) * 256 + t;     // 65536 float4s
        if (p == 0) *loss_acc = 0.0f;
        const int k  = p >> 6;
        const int fq = p & 63;
        const int dg = fq * 4;
        float4 v = *(const float4*)(W + (size_t)p * 4);
        unsigned int h0 = rne_bf16(v.x), h1 = rne_bf16(v.y), h2 = rne_bf16(v.z), h3 = rne_bf16(v.w);
        float f0 = __uint_as_float(h0 << 16), f1 = __uint_as_float(h1 << 16);
        float f2 = __uint_as_float(h2 << 16), f3 = __uint_as_float(h3 << 16);
        unsigned int l0 = rne_bf16(v.x - f0), l1 = rne_bf16(v.y - f1);
        unsigned int l2 = rne_bf16(v.z - f2), l3 = rne_bf16(v.w - f3);
        const int cb = k >> 7, fr = (k >> 4) & 7, lrow = k & 15;
        const int ch = dg >> 5;
        const int lane = lrow + ((dg >> 3) & 3) * 16;
        const size_t idx = ((size_t)((cb * 8 + ch) * 8 + fr)) * 512 + lane * 8 + ((dg >> 2) & 1) * 4;
        *(uint2*)(Wfh + idx) = make_uint2(h0 | (h1 << 16), h2 | (h3 << 16));
        *(uint2*)(Wfl + idx) = make_uint2(l0 | (l1 << 16), l2 | (l3 << 16));
        if (p < K_CODES) {
            const float4* w4 = (const float4*)(W + (size_t)p * D_DIM);
            float s = 0.0f;
#pragma unroll 8
            for (int i = 0; i < D_DIM / 4; i++) {
                float4 q = w4[i];
                s += q.x * q.x + q.y * q.y + q.z * q.z + q.w * q.w;
            }
            wsq[p] = s;
        }
        return;
    }

    // ---------------- convz part ----------------
    const int bid = blockIdx.x;            // 2048 = 32 b * 4 dblk * 16 hwblk
    const int b = bid >> 6, dblk = (bid >> 4) & 3, hwblk = bid & 15;
    const float* xb = x + ((size_t)(b * 256 + dblk * 64)) * 1024 + hwblk * 64;
#pragma unroll
    for (int i = 0; i < 4; i++) {
        int dl = i * 16 + (t >> 4);
        int hl = (t & 15) * 4;
        float4 v = *(const float4*)(xb + (size_t)dl * 1024 + hl);
        tile[dl][hl] = v.x; tile[dl][hl + 1] = v.y; tile[dl][hl + 2] = v.z; tile[dl][hl + 3] = v.w;
    }
    __syncthreads();
    const int w = t >> 6, L = t & 63;
    const int n0  = b * 1024 + hwblk * 64;
    const int nb  = n0 >> 7;
    const int frb = (n0 >> 4) & 7;         // 0 or 4 (n0 multiple of 64)
#pragma unroll
    for (int j = 0; j < 2; j++) {
        const int fb  = w * 2 + j;         // 0..7
        const int chl = fb >> 2, frl = fb & 3;
        const int dgl = chl * 32 + (L >> 4) * 8;   // local dim base for this lane
        const int r   = frl * 16 + (L & 15);       // local row
        unsigned int hi[8], lo[8];
#pragma unroll
        for (int q = 0; q < 8; q++) {
            float f = tile[dgl + q][r];
            hi[q] = rne_bf16(f);
            lo[q] = rne_bf16(f - __uint_as_float(hi[q] << 16));
        }
        uint4 hp = make_uint4(hi[0] | (hi[1] << 16), hi[2] | (hi[3] << 16),
                              hi[4] | (hi[5] << 16), hi[6] | (hi[7] << 16));
        uint4 lp = make_uint4(lo[0] | (lo[1] << 16), lo[2] | (lo[3] << 16),
                              lo[4] | (lo[5] << 16), lo[6] | (lo[7] << 16));
        const int chg = dblk * 2 + chl;
        const int frg = frb + frl;
        const size_t idx = ((size_t)((nb * 8 + chg) * 8 + frg)) * 512 + L * 8;
        *(uint4*)(Zfh + idx) = hp;
        *(uint4*)(Zfl + idx) = lp;
    }
}

// ---------------- MFMA distance GEMM + best/second argmin (R11 verbatim) ----------------
__launch_bounds__(256, 3)
__global__ void mm_argmin_kernel(const unsigned short* __restrict__ Zfh,
                                 const unsigned short* __restrict__ Zfl,
                                 const unsigned short* __restrict__ Wfh,
                                 const unsigned short* __restrict__ Wfl,
                                 const float* __restrict__ wsq, float* __restrict__ pws) {
    __shared__ float red[2][128][3];        // 3 KB (epilogue only)

    const int t = threadIdx.x;
    const int w = t >> 6, lane = t & 63;
    const int wm = w & 1, wn = w >> 1;
    // XCD-chunked bijective decode (2048 blocks, 8 XCDs round-robin by blockIdx&7)
    const int g  = blockIdx.x & 7;          // XCD
    const int s  = blockIdx.x >> 3;         // per-XCD sequence 0..255
    const int cb = s & 7;                   // 8 consecutive same-XCD slots share nb
    const int nb = g * 32 + (s >> 3);
    const int c0 = cb * 128, n0 = nb * 128;

    const int l8 = lane << 3;               // ushort offset of this lane in a frag block
    const size_t aB = (size_t)cb * 32768 + (wm * 4) * 512 + l8;   // + ch*4096 + mf*512
    const size_t bB = (size_t)nb * 32768 + (wn * 4) * 512 + l8;

    f32x4 acc[4][4];
#pragma unroll
    for (int i = 0; i < 4; i++)
#pragma unroll
        for (int j = 0; j < 4; j++) acc[i][j] = (f32x4){0.f, 0.f, 0.f, 0.f};

#define LOADF(dst_, psrc_, base_, ch_)                                        \
    _Pragma("unroll")                                                         \
    for (int f_ = 0; f_ < 4; f_++)                                            \
        dst_[f_] = *(const bf16x8*)((psrc_) + (base_) + (ch_) * 4096 + f_ * 512);

#pragma unroll
    for (int ch = 0; ch < 8; ++ch) {        // full unroll -> all indices static
        bf16x8 Ah[4], Al[4], Bh[4], Bl[4];  // 64 VGPR, single set
        LOADF(Ah, Wfh, aB, ch);
        LOADF(Bh, Zfh, bB, ch);
        LOADF(Al, Wfl, aB, ch);
        LOADF(Bl, Zfl, bB, ch);
        __builtin_amdgcn_s_setprio(1);
        // hh — 16 independent MFMAs
#pragma unroll
        for (int mf = 0; mf < 4; mf++)
#pragma unroll
            for (int nf = 0; nf < 4; nf++)
                acc[mf][nf] = __builtin_amdgcn_mfma_f32_16x16x32_bf16(Ah[mf], Bh[nf], acc[mf][nf], 0, 0, 0);
        // lh
#pragma unroll
        for (int mf = 0; mf < 4; mf++)
#pragma unroll
            for (int nf = 0; nf < 4; nf++)
                acc[mf][nf] = __builtin_amdgcn_mfma_f32_16x16x32_bf16(Al[mf], Bh[nf], acc[mf][nf], 0, 0, 0);
        // hl
#pragma unroll
        for (int mf = 0; mf < 4; mf++)
#pragma unroll
            for (int nf = 0; nf < 4; nf++)
                acc[mf][nf] = __builtin_amdgcn_mfma_f32_16x16x32_bf16(Ah[mf], Bl[nf], acc[mf][nf], 0, 0, 0);
        __builtin_amdgcn_s_setprio(0);
    }
#undef LOADF

    // ---- epilogue: scores + best/second argmin
    float ws16[16];
#pragma unroll
    for (int mf = 0; mf < 4; mf++)
#pragma unroll
        for (int r = 0; r < 4; r++)
            ws16[mf * 4 + r] = wsq[c0 + wm * 64 + mf * 16 + ((lane >> 4) << 2) + r];

    float b1[4], b2[4]; int i1[4];
#pragma unroll
    for (int nf = 0; nf < 4; nf++) {
        b1[nf] = 1e30f; b2[nf] = 1e30f; i1[nf] = 0;
#pragma unroll
        for (int mf = 0; mf < 4; mf++)
#pragma unroll
            for (int r = 0; r < 4; r++) {
                float s2 = ws16[mf * 4 + r] - 2.0f * acc[mf][nf][r];
                int code = c0 + wm * 64 + mf * 16 + ((lane >> 4) << 2) + r;
                if (s2 < b1[nf]) { b2[nf] = b1[nf]; b1[nf] = s2; i1[nf] = code; }
                else if (s2 < b2[nf]) b2[nf] = s2;
            }
    }
    // merge across the 4 k-lane-groups holding the same zrow (lane&15)
#pragma unroll
    for (int off = 16; off <= 32; off <<= 1) {
#pragma unroll
        for (int nf = 0; nf < 4; nf++) {
            float ob1 = __shfl_xor(b1[nf], off);
            float ob2 = __shfl_xor(b2[nf], off);
            int   oi1 = __shfl_xor(i1[nf], off);
            float nb2 = fminf(fminf(b2[nf], ob2), fmaxf(b1[nf], ob1));
            if (ob1 < b1[nf] || (ob1 == b1[nf] && oi1 < i1[nf])) { b1[nf] = ob1; i1[nf] = oi1; }
            b2[nf] = nb2;
        }
    }
    if ((lane >> 4) == 0) {
#pragma unroll
        for (int nf = 0; nf < 4; nf++) {
            int zr = wn * 64 + nf * 16 + (lane & 15);
            red[wm][zr][0] = b1[nf];
            red[wm][zr][1] = __int_as_float(i1[nf]);
            red[wm][zr][2] = b2[nf];
        }
    }
    __syncthreads();
    if (t < 128) {
        float a1 = red[0][t][0], ai = red[0][t][1], a2 = red[0][t][2];
        float c1 = red[1][t][0], ci = red[1][t][1], c2 = red[1][t][2];
        float m2 = fminf(fminf(a2, c2), fmaxf(a1, c1));
        float m1 = a1, mi = ai;
        if (c1 < a1) { m1 = c1; mi = ci; }   // tie keeps wm0 (lower codes)
        float* dst = pws + ((size_t)(n0 + t) * 8 + cb) * 3;
        dst[0] = m1; dst[1] = mi; dst[2] = m2;
    }
}

// ---------------- fused combine + rescore + gather + loss (2048 blocks x 16 rows) ----------------
// Phase 1 (t<16): fold 8 partials -> idx (LDS idxbuf) + out_idx_f + suspect list.
// Phase 2: exact fp32 rescore of this block's suspects (block-per-suspect, 256 thr).
// Phase 3: stream z_q + loss for flat range [b*1024, b*1024+1024) float4s:
//   4 batched iterations (all loads issued before compute), nontemporal x/z_q.
__global__ void combine_rescore_gather_kernel(const float* __restrict__ pws,
                                              const float* __restrict__ x,
                                              const float* __restrict__ W,
                                              const float* __restrict__ wsq,
                                              float* __restrict__ out_idx_f,
                                              float* __restrict__ out_zq,
                                              float* __restrict__ loss_acc) {
    __shared__ float zrow[256];
    __shared__ float rv[256];
    __shared__ int   ri[256];
    __shared__ int   slist[16];
    __shared__ int   idxbuf[16];
    __shared__ int   scnt;
    const int t = threadIdx.x;
    if (t == 0) scnt = 0;
    __syncthreads();

    // ---- phase 1: combine
    if (t < 16) {
        const int n = blockIdx.x * 16 + t;
        float b1 = 1e30f, bi = 0.f, b2 = 1e30f;
        const float* e = pws + (size_t)n * 24;
#pragma unroll
        for (int cbk = 0; cbk < 8; cbk++) {
            float e1 = e[cbk * 3 + 0], ei = e[cbk * 3 + 1], e2 = e[cbk * 3 + 2];
            float m2 = fminf(fminf(b2, e2), fmaxf(b1, e1));
            if (e1 < b1) { b1 = e1; bi = ei; }   // ties keep earlier cb (lower codes)
            b2 = m2;
        }
        int idx = __float_as_int(bi);
        idxbuf[t] = idx;
        out_idx_f[n] = (float)idx;
        if (b2 - b1 <= MARGIN) {
            int pos = atomicAdd(&scnt, 1);       // LDS atomic, block-local
            slist[pos] = n;
        }
    }
    __syncthreads();
    const int cnt = scnt;

    // ---- phase 2: exact rescore of suspects
    for (int s = 0; s < cnt; s++) {
        const int n = slist[s];
        const int b = n >> 10, hw = n & 1023;
        zrow[t] = x[(((size_t)(b * 256 + t)) << 10) + hw];
        __syncthreads();
        float best = 1e30f; int bidx = 0;
#pragma unroll
        for (int j = 0; j < 4; j++) {
            const int k = t + j * 256;           // ascending per thread
            const float4* wr = (const float4*)(W + (size_t)k * 256);
            float dot = 0.f;
#pragma unroll 16
            for (int q = 0; q < 64; q++) {
                float4 wv = wr[q];
                float4 zv = *(const float4*)&zrow[q * 4];
                dot = fmaf(wv.x, zv.x, dot); dot = fmaf(wv.y, zv.y, dot);
                dot = fmaf(wv.z, zv.z, dot); dot = fmaf(wv.w, zv.w, dot);
            }
            float sc = wsq[k] - 2.f * dot;
            if (sc < best) { best = sc; bidx = k; }
        }
        rv[t] = best; ri[t] = bidx;
        __syncthreads();
        for (int st = 128; st > 0; st >>= 1) {
            if (t < st) {
                float ov = rv[t + st]; int oi = ri[t + st];
                if (ov < rv[t] || (ov == rv[t] && oi < ri[t])) { rv[t] = ov; ri[t] = oi; }
            }
            __syncthreads();
        }
        if (t == 0) {
            idxbuf[n - blockIdx.x * 16] = ri[0];
            out_idx_f[n] = (float)ri[0];
        }
        __syncthreads();                         // zrow reads done; idxbuf visible
    }

    // ---- phase 3: gather z_q + loss for this block's flat range (batched MLP)
    const size_t base4 = (size_t)blockIdx.x * 1024;   // float4 index base (16 rows x 64)
    int kk[4];
#pragma unroll
    for (int it = 0; it < 4; it++)
        kk[it] = idxbuf[(it * 256 + t) >> 6];         // local rows 0..15

    f32x4 wv[4], xv[4];
#pragma unroll
    for (int it = 0; it < 4; it++) {
        const int q = it * 256 + t;                   // 0..1023
        const int j = (q & 63) << 2;
        const size_t p4 = base4 + q;
        wv[it] = *(const f32x4*)(W + (size_t)kk[it] * D_DIM + j);
        xv[it] = __builtin_nontemporal_load((const f32x4*)(x + p4 * 4));
    }

    float acc = 0.0f;
#pragma unroll
    for (int it = 0; it < 4; it++) {
        const size_t p4 = base4 + it * 256 + t;
        float dx = wv[it][0] - xv[it][0], dy = wv[it][1] - xv[it][1];
        float dz = wv[it][2] - xv[it][2], dw = wv[it][3] - xv[it][3];
        acc += dx * dx + dy * dy + dz * dz + dw * dw;
        __builtin_nontemporal_store(wv[it], (f32x4*)(out_zq + p4 * 4));
    }
    rv[t] = acc;
    __syncthreads();
    for (int s = 128; s > 0; s >>= 1) {
        if (t < s) rv[t] += rv[t + s];
        __syncthreads();
    }
    if (t == 0) atomicAdd(loss_acc, rv[0]);
}

// ---------------- fallback path helpers (ws too small) ----------------
__global__ void wsq_only_kernel(const float* __restrict__ W, float* __restrict__ wsq,
                                float* __restrict__ loss_acc) {
    int k = blockIdx.x * blockDim.x + threadIdx.x;
    if (k == 0) *loss_acc = 0.0f;
    if (k < K_CODES) {
        const float4* w4 = (const float4*)(W + (size_t)k * D_DIM);
        float s = 0.0f;
#pragma unroll 8
        for (int i = 0; i < D_DIM / 4; i++) {
            float4 v = w4[i];
            s += v.x * v.x + v.y * v.y + v.z * v.z + v.w * v.w;
        }
        wsq[k] = s;
    }
}

#define FROWS 64
#define FKT 256
#define FDT 32
#define FKTP 260

__launch_bounds__(256, 3)
__global__ void argmin_f32_kernel(const float* __restrict__ x, const float* __restrict__ W,
                                  const float* __restrict__ wsq,
                                  float* __restrict__ out_idx_f, int* __restrict__ ws_idx) {
    __shared__ float zT[FDT][FROWS];
    __shared__ float wT[FDT][FKTP];
    const int t = threadIdx.x;
    const int lane = t & 63;
    const int wv = t >> 6;
    const int tc = t & 31;
    const int tr = t >> 5;
    const int tr8 = tr * 8, tc4 = tc * 4;
    const int n0 = blockIdx.x * FROWS;
    const int b = n0 >> 10;
    const int hw0 = n0 & 1023;
    const size_t xbase = (size_t)b * D_DIM * 1024;
    float rmin[8]; int ridx[8];
#pragma unroll
    for (int i = 0; i < 8; i++) { rmin[i] = 1e30f; ridx[i] = 0; }
#pragma unroll 1
    for (int k0 = 0; k0 < K_CODES; k0 += FKT) {
        float acc[8][8] = {{0.f}};
#pragma unroll 1
        for (int d0 = 0; d0 < D_DIM; d0 += FDT) {
#pragma unroll
            for (int i = 0; i < 2; i++) {
                int dl0 = wv * 8 + i * 4;
                const float* src = x + xbase + ((size_t)(d0 + dl0 + (lane >> 4)) << 10)
                                 + hw0 + ((lane & 15) << 2);
                __builtin_amdgcn_global_load_lds(
                    (const __attribute__((address_space(1))) void*)src,
                    (__attribute__((address_space(3))) void*)&zT[dl0][0], 16, 0, 0);
            }
#pragma unroll
            for (int i = 0; i < 8; i++) {
                int e = t + i * 256;
                int kk = e >> 3, dg = e & 7;
                float4 v = *(const float4*)(W + (size_t)(k0 + kk) * D_DIM + d0 + dg * 4);
                wT[dg * 4 + 0][kk] = v.x; wT[dg * 4 + 1][kk] = v.y;
                wT[dg * 4 + 2][kk] = v.z; wT[dg * 4 + 3][kk] = v.w;
            }
            __syncthreads();
#pragma unroll 4
            for (int d = 0; d < FDT; d++) {
                float zr[8], wc[8];
                *(float4*)&zr[0] = *(const float4*)&zT[d][tr8];
                *(float4*)&zr[4] = *(const float4*)&zT[d][tr8 + 4];
                *(float4*)&wc[0] = *(const float4*)&wT[d][tc4];
                *(float4*)&wc[4] = *(const float4*)&wT[d][tc4 + 128];
#pragma unroll
                for (int i = 0; i < 8; i++)
#pragma unroll
                    for (int j = 0; j < 8; j++)
                        acc[i][j] = fmaf(zr[i], wc[j], acc[i][j]);
            }
            __syncthreads();
        }
#pragma unroll
        for (int g = 0; g < 2; g++)
#pragma unroll
            for (int j = 0; j < 4; j++) {
                int k = k0 + g * 128 + tc4 + j;
                float ws = wsq[k];
#pragma unroll
                for (int i = 0; i < 8; i++) {
                    float s = ws - 2.0f * acc[i][g * 4 + j];
                    if (s < rmin[i]) { rmin[i] = s; ridx[i] = k; }
                }
            }
    }
#pragma unroll
    for (int off = 1; off < 32; off <<= 1) {
#pragma unroll
        for (int i = 0; i < 8; i++) {
            float ov = __shfl_xor(rmin[i], off);
            int oi = __shfl_xor(ridx[i], off);
            if (ov < rmin[i] || (ov == rmin[i] && oi < ridx[i])) { rmin[i] = ov; ridx[i] = oi; }
        }
    }
    if (tc == 0) {
#pragma unroll
        for (int i = 0; i < 8; i++) {
            int n = n0 + tr8 + i;
            ws_idx[n] = ridx[i];
            out_idx_f[n] = (float)ridx[i];
        }
    }
}

// ---------------- fallback gather z_q + loss SSE ----------------
__global__ void gather_loss_kernel(const float* __restrict__ x, const float* __restrict__ W,
                                   const int* __restrict__ ws_idx,
                                   float* __restrict__ out_zq, float* __restrict__ loss_acc) {
    __shared__ float red[256];
    const size_t tid = (size_t)blockIdx.x * 256 + threadIdx.x;
    const size_t STRIDE = 524288;          // total threads

    int kk[4];
#pragma unroll
    for (int i = 0; i < 4; i++)
        kk[i] = ws_idx[(tid + i * STRIDE) >> 6];

    f32x4 wv[4], xv[4];
#pragma unroll
    for (int i = 0; i < 4; i++) {
        const size_t p4 = tid + i * STRIDE;
        const int j = (int)((p4 & 63) << 2);
        wv[i] = *(const f32x4*)(W + (size_t)kk[i] * D_DIM + j);
        xv[i] = __builtin_nontemporal_load((const f32x4*)(x + p4 * 4));
    }

    float acc = 0.0f;
#pragma unroll
    for (int i = 0; i < 4; i++) {
        const size_t p4 = tid + i * STRIDE;
        float dx = wv[i][0] - xv[i][0], dy = wv[i][1] - xv[i][1];
        float dz = wv[i][2] - xv[i][2], dw = wv[i][3] - xv[i][3];
        acc += dx * dx + dy * dy + dz * dz + dw * dw;
        __builtin_nontemporal_store(wv[i], (f32x4*)(out_zq + p4 * 4));
    }

    red[threadIdx.x] = acc;
    __syncthreads();
    for (int s = 128; s > 0; s >>= 1) {
        if ((int)threadIdx.x < s) red[threadIdx.x] += red[threadIdx.x + s];
        __syncthreads();
    }
    if (threadIdx.x == 0) atomicAdd(loss_acc, red[0]);
}

__global__ void finalize_kernel(const float* __restrict__ loss_acc, float* __restrict__ out_loss) {
    out_loss[0] = 1.25f * loss_acc[0] * (1.0f / 8388608.0f);
}

extern "C" void kernel_launch(void* const* d_in, const int* in_sizes, int n_in,
                              void* d_out, int out_size, void* d_ws, size_t ws_size,
                              hipStream_t stream) {
    const float* x = (const float*)d_in[0];
    const float* W = (const float*)d_in[1];

    float* out      = (float*)d_out;
    float* out_zq   = out;                         // 8388608 f32
    float* out_idx  = out + 8388608;               // 32768 f32
    float* out_loss = out + 8388608 + 32768;       // 1 f32

    // workspace layout
    float* loss_acc = (float*)d_ws;                              // @0
    float* wsq      = (float*)((char*)d_ws + 1024);              // 4 KB
    int*   ws_idx   = (int*)((char*)d_ws + 8192);                // 128 KB
    unsigned short* Wfh = (unsigned short*)((char*)d_ws + 270336);  // 512 KB
    unsigned short* Wfl = (unsigned short*)((char*)d_ws + 794624);  // 512 KB
    float* pws      = (float*)((char*)d_ws + 1318912);           // 3 MB
    const size_t NEEDED = 4464640;

    if (ws_size >= NEEDED) {
        // Zfh/Zfl fragment-major bf16 live in the out_zq region (2 x 16.78 MB);
        // the fused gather phase overwrites them afterwards.
        unsigned short* Zfh = (unsigned short*)out_zq;
        unsigned short* Zfl = Zfh + (size_t)N_ROWS * D_DIM;

        prep_convz_kernel<<<2304, 256, 0, stream>>>(x, W, wsq, Wfh, Wfl, Zfh, Zfl, loss_acc);
        mm_argmin_kernel<<<2048, 256, 0, stream>>>(Zfh, Zfl, Wfh, Wfl, wsq, pws);
        combine_rescore_gather_kernel<<<2048, 256, 0, stream>>>(pws, x, W, wsq,
                                                                out_idx, out_zq, loss_acc);
        finalize_kernel<<<1, 1, 0, stream>>>(loss_acc, out_loss);
    } else {
        wsq_only_kernel<<<4, 256, 0, stream>>>(W, wsq, loss_acc);
        argmin_f32_kernel<<<N_ROWS / FROWS, 256, 0, stream>>>(x, W, wsq, out_idx, ws_idx);
        gather_loss_kernel<<<2048, 256, 0, stream>>>(x, W, ws_idx, out_zq, loss_acc);
        finalize_kernel<<<1, 1, 0, stream>>>(loss_acc, out_loss);
    }
}

// Round 23
// 111.625 us; speedup vs baseline: 1.1563x; 1.1563x over previous
//
#include <hip/hip_runtime.h>

// VQ-VAE codebook quantization — R23: R20's proven 512-block crg geometry +
//   (1) 64-slot loss accumulator (same-address atomic serialization fix),
//   (2) no nontemporal hint on x loads (keep on z_q stores),
//   (3) 4-deep batched phase-3 loads. mm = R11 verbatim. 4 launches.
//   x: [32, 256, 32, 32] f32 -> z: [N=32768, D=256]; W: [1024, 256] f32
//   idx[n] = argmin_k (|w_k|^2 - 2 z_n.w_k)
//   bf16 3-term split (per-chunk: hh, lh, hl); rows with (second - best) <= MARGIN
//   exactly rescored in fp32 (MARGIN = 0.0039 ~ 5.7 sigma of split error).
// Fragment-major global layout: each 16-row x 32-dim MFMA fragment is 1 KB
// contiguous in exact lane order (ushort idx = ((tile*8 + ch)*8 + fr)*512 + lane*8).
// Outputs flat f32: z_q (8388608), idx-as-float (32768), loss (1)

#define N_ROWS 32768
#define K_CODES 1024
#define D_DIM 256
#define MARGIN 0.00390625f

using f32x4  = __attribute__((ext_vector_type(4))) float;
using bf16x8 = __attribute__((ext_vector_type(8))) short;

__device__ __forceinline__ unsigned int rne_bf16(float f) {
    unsigned int u = __float_as_uint(f);
    return (u + 0x7FFFu + ((u >> 16) & 1u)) >> 16;   // round-to-nearest-even bf16 bits
}

// ---------------- fused: convz (blocks 0..2047) + prep (blocks 2048..2303) ----------------
__global__ void prep_convz_kernel(const float* __restrict__ x, const float* __restrict__ W,
                                  float* __restrict__ wsq,
                                  unsigned short* __restrict__ Wfh, unsigned short* __restrict__ Wfl,
                                  unsigned short* __restrict__ Zfh, unsigned short* __restrict__ Zfl,
                                  float* __restrict__ loss_slots) {
    __shared__ float tile[64][65];
    const int t = threadIdx.x;

    if (blockIdx.x >= 2048) {
        // ---------------- prep part ----------------
        int p = (blockIdx.x - 2048) * 256 + t;     // 65536 float4s
        if (p < 64) loss_slots[p] = 0.0f;
        const int k  = p >> 6;
        const int fq = p & 63;
        const int dg = fq * 4;
        float4 v = *(const float4*)(W + (size_t)p * 4);
        unsigned int h0 = rne_bf16(v.x), h1 = rne_bf16(v.y), h2 = rne_bf16(v.z), h3 = rne_bf16(v.w);
        float f0 = __uint_as_float(h0 << 16), f1 = __uint_as_float(h1 << 16);
        float f2 = __uint_as_float(h2 << 16), f3 = __uint_as_float(h3 << 16);
        unsigned int l0 = rne_bf16(v.x - f0), l1 = rne_bf16(v.y - f1);
        unsigned int l2 = rne_bf16(v.z - f2), l3 = rne_bf16(v.w - f3);
        const int cb = k >> 7, fr = (k >> 4) & 7, lrow = k & 15;
        const int ch = dg >> 5;
        const int lane = lrow + ((dg >> 3) & 3) * 16;
        const size_t idx = ((size_t)((cb * 8 + ch) * 8 + fr)) * 512 + lane * 8 + ((dg >> 2) & 1) * 4;
        *(uint2*)(Wfh + idx) = make_uint2(h0 | (h1 << 16), h2 | (h3 << 16));
        *(uint2*)(Wfl + idx) = make_uint2(l0 | (l1 << 16), l2 | (l3 << 16));
        if (p < K_CODES) {
            const float4* w4 = (const float4*)(W + (size_t)p * D_DIM);
            float s = 0.0f;
#pragma unroll 8
            for (int i = 0; i < D_DIM / 4; i++) {
                float4 q = w4[i];
                s += q.x * q.x + q.y * q.y + q.z * q.z + q.w * q.w;
            }
            wsq[p] = s;
        }
        return;
    }

    // ---------------- convz part ----------------
    const int bid = blockIdx.x;            // 2048 = 32 b * 4 dblk * 16 hwblk
    const int b = bid >> 6, dblk = (bid >> 4) & 3, hwblk = bid & 15;
    const float* xb = x + ((size_t)(b * 256 + dblk * 64)) * 1024 + hwblk * 64;
#pragma unroll
    for (int i = 0; i < 4; i++) {
        int dl = i * 16 + (t >> 4);
        int hl = (t & 15) * 4;
        float4 v = *(const float4*)(xb + (size_t)dl * 1024 + hl);
        tile[dl][hl] = v.x; tile[dl][hl + 1] = v.y; tile[dl][hl + 2] = v.z; tile[dl][hl + 3] = v.w;
    }
    __syncthreads();
    const int w = t >> 6, L = t & 63;
    const int n0  = b * 1024 + hwblk * 64;
    const int nb  = n0 >> 7;
    const int frb = (n0 >> 4) & 7;         // 0 or 4 (n0 multiple of 64)
#pragma unroll
    for (int j = 0; j < 2; j++) {
        const int fb  = w * 2 + j;         // 0..7
        const int chl = fb >> 2, frl = fb & 3;
        const int dgl = chl * 32 + (L >> 4) * 8;   // local dim base for this lane
        const int r   = frl * 16 + (L & 15);       // local row
        unsigned int hi[8], lo[8];
#pragma unroll
        for (int q = 0; q < 8; q++) {
            float f = tile[dgl + q][r];
            hi[q] = rne_bf16(f);
            lo[q] = rne_bf16(f - __uint_as_float(hi[q] << 16));
        }
        uint4 hp = make_uint4(hi[0] | (hi[1] << 16), hi[2] | (hi[3] << 16),
                              hi[4] | (hi[5] << 16), hi[6] | (hi[7] << 16));
        uint4 lp = make_uint4(lo[0] | (lo[1] << 16), lo[2] | (lo[3] << 16),
                              lo[4] | (lo[5] << 16), lo[6] | (lo[7] << 16));
        const int chg = dblk * 2 + chl;
        const int frg = frb + frl;
        const size_t idx = ((size_t)((nb * 8 + chg) * 8 + frg)) * 512 + L * 8;
        *(uint4*)(Zfh + idx) = hp;
        *(uint4*)(Zfl + idx) = lp;
    }
}

// ---------------- MFMA distance GEMM + best/second argmin (R11 verbatim) ----------------
__launch_bounds__(256, 3)
__global__ void mm_argmin_kernel(const unsigned short* __restrict__ Zfh,
                                 const unsigned short* __restrict__ Zfl,
                                 const unsigned short* __restrict__ Wfh,
                                 const unsigned short* __restrict__ Wfl,
                                 const float* __restrict__ wsq, float* __restrict__ pws) {
    __shared__ float red[2][128][3];        // 3 KB (epilogue only)

    const int t = threadIdx.x;
    const int w = t >> 6, lane = t & 63;
    const int wm = w & 1, wn = w >> 1;
    // XCD-chunked bijective decode (2048 blocks, 8 XCDs round-robin by blockIdx&7)
    const int g  = blockIdx.x & 7;          // XCD
    const int s  = blockIdx.x >> 3;         // per-XCD sequence 0..255
    const int cb = s & 7;                   // 8 consecutive same-XCD slots share nb
    const int nb = g * 32 + (s >> 3);
    const int c0 = cb * 128, n0 = nb * 128;

    const int l8 = lane << 3;               // ushort offset of this lane in a frag block
    const size_t aB = (size_t)cb * 32768 + (wm * 4) * 512 + l8;   // + ch*4096 + mf*512
    const size_t bB = (size_t)nb * 32768 + (wn * 4) * 512 + l8;

    f32x4 acc[4][4];
#pragma unroll
    for (int i = 0; i < 4; i++)
#pragma unroll
        for (int j = 0; j < 4; j++) acc[i][j] = (f32x4){0.f, 0.f, 0.f, 0.f};

#define LOADF(dst_, psrc_, base_, ch_)                                        \
    _Pragma("unroll")                                                         \
    for (int f_ = 0; f_ < 4; f_++)                                            \
        dst_[f_] = *(const bf16x8*)((psrc_) + (base_) + (ch_) * 4096 + f_ * 512);

#pragma unroll
    for (int ch = 0; ch < 8; ++ch) {        // full unroll -> all indices static
        bf16x8 Ah[4], Al[4], Bh[4], Bl[4];  // 64 VGPR, single set
        LOADF(Ah, Wfh, aB, ch);
        LOADF(Bh, Zfh, bB, ch);
        LOADF(Al, Wfl, aB, ch);
        LOADF(Bl, Zfl, bB, ch);
        __builtin_amdgcn_s_setprio(1);
        // hh — 16 independent MFMAs
#pragma unroll
        for (int mf = 0; mf < 4; mf++)
#pragma unroll
            for (int nf = 0; nf < 4; nf++)
                acc[mf][nf] = __builtin_amdgcn_mfma_f32_16x16x32_bf16(Ah[mf], Bh[nf], acc[mf][nf], 0, 0, 0);
        // lh
#pragma unroll
        for (int mf = 0; mf < 4; mf++)
#pragma unroll
            for (int nf = 0; nf < 4; nf++)
                acc[mf][nf] = __builtin_amdgcn_mfma_f32_16x16x32_bf16(Al[mf], Bh[nf], acc[mf][nf], 0, 0, 0);
        // hl
#pragma unroll
        for (int mf = 0; mf < 4; mf++)
#pragma unroll
            for (int nf = 0; nf < 4; nf++)
                acc[mf][nf] = __builtin_amdgcn_mfma_f32_16x16x32_bf16(Ah[mf], Bl[nf], acc[mf][nf], 0, 0, 0);
        __builtin_amdgcn_s_setprio(0);
    }
#undef LOADF

    // ---- epilogue: scores + best/second argmin
    float ws16[16];
#pragma unroll
    for (int mf = 0; mf < 4; mf++)
#pragma unroll
        for (int r = 0; r < 4; r++)
            ws16[mf * 4 + r] = wsq[c0 + wm * 64 + mf * 16 + ((lane >> 4) << 2) + r];

    float b1[4], b2[4]; int i1[4];
#pragma unroll
    for (int nf = 0; nf < 4; nf++) {
        b1[nf] = 1e30f; b2[nf] = 1e30f; i1[nf] = 0;
#pragma unroll
        for (int mf = 0; mf < 4; mf++)
#pragma unroll
            for (int r = 0; r < 4; r++) {
                float s2 = ws16[mf * 4 + r] - 2.0f * acc[mf][nf][r];
                int code = c0 + wm * 64 + mf * 16 + ((lane >> 4) << 2) + r;
                if (s2 < b1[nf]) { b2[nf] = b1[nf]; b1[nf] = s2; i1[nf] = code; }
                else if (s2 < b2[nf]) b2[nf] = s2;
            }
    }
    // merge across the 4 k-lane-groups holding the same zrow (lane&15)
#pragma unroll
    for (int off = 16; off <= 32; off <<= 1) {
#pragma unroll
        for (int nf = 0; nf < 4; nf++) {
            float ob1 = __shfl_xor(b1[nf], off);
            float ob2 = __shfl_xor(b2[nf], off);
            int   oi1 = __shfl_xor(i1[nf], off);
            float nb2 = fminf(fminf(b2[nf], ob2), fmaxf(b1[nf], ob1));
            if (ob1 < b1[nf] || (ob1 == b1[nf] && oi1 < i1[nf])) { b1[nf] = ob1; i1[nf] = oi1; }
            b2[nf] = nb2;
        }
    }
    if ((lane >> 4) == 0) {
#pragma unroll
        for (int nf = 0; nf < 4; nf++) {
            int zr = wn * 64 + nf * 16 + (lane & 15);
            red[wm][zr][0] = b1[nf];
            red[wm][zr][1] = __int_as_float(i1[nf]);
            red[wm][zr][2] = b2[nf];
        }
    }
    __syncthreads();
    if (t < 128) {
        float a1 = red[0][t][0], ai = red[0][t][1], a2 = red[0][t][2];
        float c1 = red[1][t][0], ci = red[1][t][1], c2 = red[1][t][2];
        float m2 = fminf(fminf(a2, c2), fmaxf(a1, c1));
        float m1 = a1, mi = ai;
        if (c1 < a1) { m1 = c1; mi = ci; }   // tie keeps wm0 (lower codes)
        float* dst = pws + ((size_t)(n0 + t) * 8 + cb) * 3;
        dst[0] = m1; dst[1] = mi; dst[2] = m2;
    }
}

// ---------------- fused combine + rescore + gather + loss (512 blocks x 64 rows) ----------------
// Phase 1 (t<64): fold 8 partials -> idx (LDS idxbuf) + out_idx_f + suspect list.
// Phase 2: exact fp32 rescore of this block's suspects (block-per-suspect, 256 thr).
// Phase 3: stream z_q + loss for flat range [b*16384, b*16384+16384): 16 f4-iters
//   in 4 batched groups (MLP); plain x loads (L3-hot on replay), nontemporal z_q
//   stores; loss into 64 slots (atomic contention fix).
__global__ void combine_rescore_gather_kernel(const float* __restrict__ pws,
                                              const float* __restrict__ x,
                                              const float* __restrict__ W,
                                              const float* __restrict__ wsq,
                                              float* __restrict__ out_idx_f,
                                              float* __restrict__ out_zq,
                                              float* __restrict__ loss_slots) {
    __shared__ float zrow[256];
    __shared__ float rv[256];
    __shared__ int   ri[256];
    __shared__ int   slist[64];
    __shared__ int   idxbuf[64];
    __shared__ int   scnt;
    const int t = threadIdx.x;
    if (t == 0) scnt = 0;
    __syncthreads();

    // ---- phase 1: combine
    if (t < 64) {
        const int n = blockIdx.x * 64 + t;
        float b1 = 1e30f, bi = 0.f, b2 = 1e30f;
        const float* e = pws + (size_t)n * 24;
#pragma unroll
        for (int cbk = 0; cbk < 8; cbk++) {
            float e1 = e[cbk * 3 + 0], ei = e[cbk * 3 + 1], e2 = e[cbk * 3 + 2];
            float m2 = fminf(fminf(b2, e2), fmaxf(b1, e1));
            if (e1 < b1) { b1 = e1; bi = ei; }   // ties keep earlier cb (lower codes)
            b2 = m2;
        }
        int idx = __float_as_int(bi);
        idxbuf[t] = idx;
        out_idx_f[n] = (float)idx;
        if (b2 - b1 <= MARGIN) {
            int pos = atomicAdd(&scnt, 1);       // LDS atomic, block-local
            slist[pos] = n;
        }
    }
    __syncthreads();
    const int cnt = scnt;

    // ---- phase 2: exact rescore of suspects
    for (int s = 0; s < cnt; s++) {
        const int n = slist[s];
        const int b = n >> 10, hw = n & 1023;
        zrow[t] = x[(((size_t)(b * 256 + t)) << 10) + hw];
        __syncthreads();
        float best = 1e30f; int bidx = 0;
#pragma unroll
        for (int j = 0; j < 4; j++) {
            const int k = t + j * 256;           // ascending per thread
            const float4* wr = (const float4*)(W + (size_t)k * 256);
            float dot = 0.f;
#pragma unroll 16
            for (int q = 0; q < 64; q++) {
                float4 wv = wr[q];
                float4 zv = *(const float4*)&zrow[q * 4];
                dot = fmaf(wv.x, zv.x, dot); dot = fmaf(wv.y, zv.y, dot);
                dot = fmaf(wv.z, zv.z, dot); dot = fmaf(wv.w, zv.w, dot);
            }
            float sc = wsq[k] - 2.f * dot;
            if (sc < best) { best = sc; bidx = k; }
        }
        rv[t] = best; ri[t] = bidx;
        __syncthreads();
        for (int st = 128; st > 0; st >>= 1) {
            if (t < st) {
                float ov = rv[t + st]; int oi = ri[t + st];
                if (ov < rv[t] || (ov == rv[t] && oi < ri[t])) { rv[t] = ov; ri[t] = oi; }
            }
            __syncthreads();
        }
        if (t == 0) {
            idxbuf[n - blockIdx.x * 64] = ri[0];
            out_idx_f[n] = (float)ri[0];
        }
        __syncthreads();                         // zrow reads done; idxbuf visible
    }

    // ---- phase 3: gather z_q + loss (4 batched groups of 4 f4-iterations)
    const size_t base4 = (size_t)blockIdx.x * 4096;   // float4 index base (64 rows x 64)
    float acc = 0.0f;
#pragma unroll
    for (int gr = 0; gr < 4; gr++) {
        int kk[4];
        f32x4 wv[4], xv[4];
#pragma unroll
        for (int u = 0; u < 4; u++) {
            const int q = (gr * 4 + u) * 256 + t;     // 0..4095
            kk[u] = idxbuf[q >> 6];
        }
#pragma unroll
        for (int u = 0; u < 4; u++) {
            const int q = (gr * 4 + u) * 256 + t;
            const int j = (q & 63) << 2;
            wv[u] = *(const f32x4*)(W + (size_t)kk[u] * D_DIM + j);
            xv[u] = *(const f32x4*)(x + (base4 + q) * 4);       // plain load (L3-hot)
        }
#pragma unroll
        for (int u = 0; u < 4; u++) {
            const size_t p4 = base4 + (gr * 4 + u) * 256 + t;
            float dx = wv[u][0] - xv[u][0], dy = wv[u][1] - xv[u][1];
            float dz = wv[u][2] - xv[u][2], dw = wv[u][3] - xv[u][3];
            acc += dx * dx + dy * dy + dz * dz + dw * dw;
            __builtin_nontemporal_store(wv[u], (f32x4*)(out_zq + p4 * 4));
        }
    }
    rv[t] = acc;
    __syncthreads();
    for (int s = 128; s > 0; s >>= 1) {
        if (t < s) rv[t] += rv[t + s];
        __syncthreads();
    }
    if (t == 0) atomicAdd(&loss_slots[blockIdx.x & 63], rv[0]);
}

// ---------------- fallback path helpers (ws too small) ----------------
__global__ void wsq_only_kernel(const float* __restrict__ W, float* __restrict__ wsq,
                                float* __restrict__ loss_slots) {
    int k = blockIdx.x * blockDim.x + threadIdx.x;
    if (k < 64) loss_slots[k] = 0.0f;
    if (k < K_CODES) {
        const float4* w4 = (const float4*)(W + (size_t)k * D_DIM);
        float s = 0.0f;
#pragma unroll 8
        for (int i = 0; i < D_DIM / 4; i++) {
            float4 v = w4[i];
            s += v.x * v.x + v.y * v.y + v.z * v.z + v.w * v.w;
        }
        wsq[k] = s;
    }
}

#define FROWS 64
#define FKT 256
#define FDT 32
#define FKTP 260

__launch_bounds__(256, 3)
__global__ void argmin_f32_kernel(const float* __restrict__ x, const float* __restrict__ W,
                                  const float* __restrict__ wsq,
                                  float* __restrict__ out_idx_f, int* __restrict__ ws_idx) {
    __shared__ float zT[FDT][FROWS];
    __shared__ float wT[FDT][FKTP];
    const int t = threadIdx.x;
    const int lane = t & 63;
    const int wv = t >> 6;
    const int tc = t & 31;
    const int tr = t >> 5;
    const int tr8 = tr * 8, tc4 = tc * 4;
    const int n0 = blockIdx.x * FROWS;
    const int b = n0 >> 10;
    const int hw0 = n0 & 1023;
    const size_t xbase = (size_t)b * D_DIM * 1024;
    float rmin[8]; int ridx[8];
#pragma unroll
    for (int i = 0; i < 8; i++) { rmin[i] = 1e30f; ridx[i] = 0; }
#pragma unroll 1
    for (int k0 = 0; k0 < K_CODES; k0 += FKT) {
        float acc[8][8] = {{0.f}};
#pragma unroll 1
        for (int d0 = 0; d0 < D_DIM; d0 += FDT) {
#pragma unroll
            for (int i = 0; i < 2; i++) {
                int dl0 = wv * 8 + i * 4;
                const float* src = x + xbase + ((size_t)(d0 + dl0 + (lane >> 4)) << 10)
                                 + hw0 + ((lane & 15) << 2);
                __builtin_amdgcn_global_load_lds(
                    (const __attribute__((address_space(1))) void*)src,
                    (__attribute__((address_space(3))) void*)&zT[dl0][0], 16, 0, 0);
            }
#pragma unroll
            for (int i = 0; i < 8; i++) {
                int e = t + i * 256;
                int kk = e >> 3, dg = e & 7;
                float4 v = *(const float4*)(W + (size_t)(k0 + kk) * D_DIM + d0 + dg * 4);
                wT[dg * 4 + 0][kk] = v.x; wT[dg * 4 + 1][kk] = v.y;
                wT[dg * 4 + 2][kk] = v.z; wT[dg * 4 + 3][kk] = v.w;
            }
            __syncthreads();
#pragma unroll 4
            for (int d = 0; d < FDT; d++) {
                float zr[8], wc[8];
                *(float4*)&zr[0] = *(const float4*)&zT[d][tr8];
                *(float4*)&zr[4] = *(const float4*)&zT[d][tr8 + 4];
                *(float4*)&wc[0] = *(const float4*)&wT[d][tc4];
                *(float4*)&wc[4] = *(const float4*)&wT[d][tc4 + 128];
#pragma unroll
                for (int i = 0; i < 8; i++)
#pragma unroll
                    for (int j = 0; j < 8; j++)
                        acc[i][j] = fmaf(zr[i], wc[j], acc[i][j]);
            }
            __syncthreads();
        }
#pragma unroll
        for (int g = 0; g < 2; g++)
#pragma unroll
            for (int j = 0; j < 4; j++) {
                int k = k0 + g * 128 + tc4 + j;
                float ws = wsq[k];
#pragma unroll
                for (int i = 0; i < 8; i++) {
                    float s = ws - 2.0f * acc[i][g * 4 + j];
                    if (s < rmin[i]) { rmin[i] = s; ridx[i] = k; }
                }
            }
    }
#pragma unroll
    for (int off = 1; off < 32; off <<= 1) {
#pragma unroll
        for (int i = 0; i < 8; i++) {
            float ov = __shfl_xor(rmin[i], off);
            int oi = __shfl_xor(ridx[i], off);
            if (ov < rmin[i] || (ov == rmin[i] && oi < ridx[i])) { rmin[i] = ov; ridx[i] = oi; }
        }
    }
    if (tc == 0) {
#pragma unroll
        for (int i = 0; i < 8; i++) {
            int n = n0 + tr8 + i;
            ws_idx[n] = ridx[i];
            out_idx_f[n] = (float)ridx[i];
        }
    }
}

// ---------------- fallback gather z_q + loss SSE ----------------
__global__ void gather_loss_kernel(const float* __restrict__ x, const float* __restrict__ W,
                                   const int* __restrict__ ws_idx,
                                   float* __restrict__ out_zq, float* __restrict__ loss_slots) {
    __shared__ float red[256];
    const size_t tid = (size_t)blockIdx.x * 256 + threadIdx.x;
    const size_t STRIDE = 524288;          // total threads

    int kk[4];
#pragma unroll
    for (int i = 0; i < 4; i++)
        kk[i] = ws_idx[(tid + i * STRIDE) >> 6];

    f32x4 wv[4], xv[4];
#pragma unroll
    for (int i = 0; i < 4; i++) {
        const size_t p4 = tid + i * STRIDE;
        const int j = (int)((p4 & 63) << 2);
        wv[i] = *(const f32x4*)(W + (size_t)kk[i] * D_DIM + j);
        xv[i] = *(const f32x4*)(x + p4 * 4);
    }

    float acc = 0.0f;
#pragma unroll
    for (int i = 0; i < 4; i++) {
        const size_t p4 = tid + i * STRIDE;
        float dx = wv[i][0] - xv[i][0], dy = wv[i][1] - xv[i][1];
        float dz = wv[i][2] - xv[i][2], dw = wv[i][3] - xv[i][3];
        acc += dx * dx + dy * dy + dz * dz + dw * dw;
        __builtin_nontemporal_store(wv[i], (f32x4*)(out_zq + p4 * 4));
    }

    red[threadIdx.x] = acc;
    __syncthreads();
    for (int s = 128; s > 0; s >>= 1) {
        if ((int)threadIdx.x < s) red[threadIdx.x] += red[threadIdx.x + s];
        __syncthreads();
    }
    if (threadIdx.x == 0) atomicAdd(&loss_slots[blockIdx.x & 63], red[0]);
}

__global__ void finalize_kernel(const float* __restrict__ loss_slots, float* __restrict__ out_loss) {
    float s = 0.0f;
#pragma unroll
    for (int i = 0; i < 64; i++) s += loss_slots[i];
    out_loss[0] = 1.25f * s * (1.0f / 8388608.0f);
}

extern "C" void kernel_launch(void* const* d_in, const int* in_sizes, int n_in,
                              void* d_out, int out_size, void* d_ws, size_t ws_size,
                              hipStream_t stream) {
    const float* x = (const float*)d_in[0];
    const float* W = (const float*)d_in[1];

    float* out      = (float*)d_out;
    float* out_zq   = out;                         // 8388608 f32
    float* out_idx  = out + 8388608;               // 32768 f32
    float* out_loss = out + 8388608 + 32768;       // 1 f32

    // workspace layout
    float* loss_slots = (float*)d_ws;                            // @0, 64 floats
    float* wsq      = (float*)((char*)d_ws + 1024);              // 4 KB
    int*   ws_idx   = (int*)((char*)d_ws + 8192);                // 128 KB
    unsigned short* Wfh = (unsigned short*)((char*)d_ws + 270336);  // 512 KB
    unsigned short* Wfl = (unsigned short*)((char*)d_ws + 794624);  // 512 KB
    float* pws      = (float*)((char*)d_ws + 1318912);           // 3 MB
    const size_t NEEDED = 4464640;

    if (ws_size >= NEEDED) {
        // Zfh/Zfl fragment-major bf16 live in the out_zq region (2 x 16.78 MB);
        // the fused gather phase overwrites them afterwards.
        unsigned short* Zfh = (unsigned short*)out_zq;
        unsigned short* Zfl = Zfh + (size_t)N_ROWS * D_DIM;

        prep_convz_kernel<<<2304, 256, 0, stream>>>(x, W, wsq, Wfh, Wfl, Zfh, Zfl, loss_slots);
        mm_argmin_kernel<<<2048, 256, 0, stream>>>(Zfh, Zfl, Wfh, Wfl, wsq, pws);
        combine_rescore_gather_kernel<<<512, 256, 0, stream>>>(pws, x, W, wsq,
                                                               out_idx, out_zq, loss_slots);
        finalize_kernel<<<1, 1, 0, stream>>>(loss_slots, out_loss);
    } else {
        wsq_only_kernel<<<4, 256, 0, stream>>>(W, wsq, loss_slots);
        argmin_f32_kernel<<<N_ROWS / FROWS, 256, 0, stream>>>(x, W, wsq, out_idx, ws_idx);
        gather_loss_kernel<<<2048, 256, 0, stream>>>(x, W, ws_idx, out_zq, loss_slots);
        finalize_kernel<<<1, 1, 0, stream>>>(loss_slots, out_loss);
    }
}